// Round 25
// baseline (146.780 us; speedup 1.0000x reference)
//
#include <hip/hip_runtime.h>
#include <cstdint>
#include <cstddef>

#define S 8192
#define Dm 1024
#define E 64
#define CAP 128
#define SEC 67108864ull   // S*E*CAP
// out layout (float32 elements), out_size = 1 + 2*SEC + 64 = 134,217,793:
//   [0] l_aux | [1,1+SEC) combine | [1+SEC,1+2SEC) dispatch | [1+2SEC,+64) counts
// Coverage map (every element written every call):
//   K1 fill: elements [4+SEC, 134217792) zeroed (chunks [B0,N4END)) + scalar
//            zeros at out[1+SEC..3+SEC]   (counts zeros harmlessly overwritten)
//   K2 bid<2048: combine elements [1,1+SEC) final values + dispatch ones
//   K2 bid==2048: counts[0..63] (incl. element 134217792) + out[0]=l_aux

#define GEMM_BLOCKS 256   // 32 tokens x 64 experts (R17/R21-verified MFMA GEMM)
#define FILL_BLOCKS 1792
#define B0 16777217u      // first aligned chunk of the dispatch-half fill
#define CH 9363u          // ceil((N4END-B0) / FILL_BLOCKS)
#define N4END 33554448u
#define WSCALE 4096.0f
#define INV_WSCALE (1.0f / 4096.0f)

typedef float f32x4 __attribute__((ext_vector_type(4)));
typedef _Float16 f16x4 __attribute__((ext_vector_type(4)));
typedef _Float16 f16x8 __attribute__((ext_vector_type(8)));

#define CV4(H, L, ROW, COL, V, SCALE) do {                                     \
    f16x4 hh, ll; float t_;                                                    \
    t_ = (V).x * (SCALE); hh[0] = (_Float16)t_; ll[0] = (_Float16)(t_ - (float)hh[0]); \
    t_ = (V).y * (SCALE); hh[1] = (_Float16)t_; ll[1] = (_Float16)(t_ - (float)hh[1]); \
    t_ = (V).z * (SCALE); hh[2] = (_Float16)t_; ll[2] = (_Float16)(t_ - (float)hh[2]); \
    t_ = (V).w * (SCALE); hh[3] = (_Float16)t_; ll[3] = (_Float16)(t_ - (float)hh[3]); \
    *(f16x4*)&H[ROW][COL] = hh;                                                \
    *(f16x4*)&L[ROW][COL] = ll;                                                \
} while (0)

// ---------------- K1: MFMA GEMM+softmax (R21 champion, verbatim) -------------
// Epilogue writes the expert histogram TRANSPOSED: cnt_gT[e][block] — so the
// merge kernel's prefix reads are lane-consecutive (R24's regression was the
// untransposed stride-256B reads: ~2M cache-line requests, ~+16us).
__global__ __launch_bounds__(512) void k_main(const float* __restrict__ x,
                                              const float* __restrict__ w,
                                              float* __restrict__ gate,
                                              int* __restrict__ idx,
                                              float* __restrict__ me_part,
                                              int* __restrict__ cnt_gT,
                                              float* __restrict__ out) {
    int bid = blockIdx.x;
    int tid = threadIdx.x;
    if (bid < GEMM_BLOCKS) {
        __shared__ _Float16 Ah[32][72];
        __shared__ _Float16 Alo[32][72];
        __shared__ _Float16 Wh[64][72];
        __shared__ _Float16 Wlo[64][72];
        __shared__ float Sl[32][66];
        __shared__ float sm[32];
        __shared__ float sinv[32];
        __shared__ int sidx[32];
        int t0 = bid * 32;
        int ar = tid >> 4;                 // 0..31
        int ac = (tid & 15) * 4;
        int wr = tid >> 3;                 // 0..63
        int wc = (tid & 7) * 8;
        const float* asrc = x + (size_t)(t0 + ar) * Dm + ac;
        const float* wsrc = w + (size_t)wr * Dm + wc;

        int wv = tid >> 6;
        int l = tid & 63;
        int lr = l & 15;
        int lg = l >> 4;
        int mt = wv & 1;
        int nt = wv >> 1;
        f32x4 acc = {0.f, 0.f, 0.f, 0.f};

        float4 pa = *(const float4*)(asrc + 0);
        float4 pw0 = *(const float4*)(wsrc + 0);
        float4 pw1 = *(const float4*)(wsrc + 4);
        float4 qa = *(const float4*)(asrc + 64);
        float4 qw0 = *(const float4*)(wsrc + 64);
        float4 qw1 = *(const float4*)(wsrc + 68);

#define WRITE_LDS(A, W0, W1)                                                   \
        CV4(Ah, Alo, ar, ac, A, 1.0f);                                         \
        CV4(Wh, Wlo, wr, wc, W0, WSCALE);                                      \
        CV4(Wh, Wlo, wr, (wc + 4), W1, WSCALE);
#define LOADP(KB)                                                              \
        pa = *(const float4*)(asrc + (KB));                                    \
        pw0 = *(const float4*)(wsrc + (KB));                                   \
        pw1 = *(const float4*)(wsrc + (KB) + 4);
#define LOADQ(KB)                                                              \
        qa = *(const float4*)(asrc + (KB));                                    \
        qw0 = *(const float4*)(wsrc + (KB));                                   \
        qw1 = *(const float4*)(wsrc + (KB) + 4);
#define INNER_MFMA                                                             \
        _Pragma("unroll")                                                      \
        for (int ks = 0; ks < 2; ++ks) {                                       \
            int kc = ks * 32 + lg * 8;                                         \
            f16x8 ah = *(const f16x8*)&Ah[mt * 16 + lr][kc];                   \
            f16x8 al = *(const f16x8*)&Alo[mt * 16 + lr][kc];                  \
            f16x8 bh = *(const f16x8*)&Wh[nt * 16 + lr][kc];                   \
            f16x8 bl = *(const f16x8*)&Wlo[nt * 16 + lr][kc];                  \
            acc = __builtin_amdgcn_mfma_f32_16x16x32_f16(ah, bh, acc, 0, 0, 0); \
            acc = __builtin_amdgcn_mfma_f32_16x16x32_f16(al, bh, acc, 0, 0, 0); \
            acc = __builtin_amdgcn_mfma_f32_16x16x32_f16(ah, bl, acc, 0, 0, 0); \
        }

        for (int ch = 0; ch < 16; ch += 2) {
            __syncthreads();
            WRITE_LDS(pa, pw0, pw1)
            __syncthreads();
            if (ch + 2 < 16) { LOADP((ch + 2) * 64) }
            INNER_MFMA
            __syncthreads();
            WRITE_LDS(qa, qw0, qw1)
            __syncthreads();
            if (ch + 3 < 16) { LOADQ((ch + 3) * 64) }
            INNER_MFMA
        }
#undef WRITE_LDS
#undef LOADP
#undef LOADQ
#undef INNER_MFMA
        __syncthreads();
        // D -> Sl (R16/R17-verified C/D layout: row = lg*4 + r, col = lr)
#pragma unroll
        for (int r = 0; r < 4; ++r)
            Sl[mt * 16 + lg * 4 + r][nt * 16 + lr] = acc[r] * INV_WSCALE;
        __syncthreads();
        if (tid < 32) {   // row phase: first-index argmax + exp-sum
            float m = Sl[tid][0];
            int am = 0;
#pragma unroll
            for (int c = 1; c < E; ++c) {
                float v = Sl[tid][c];
                if (v > m) { m = v; am = c; }
            }
            float ssum = 0.f;
#pragma unroll
            for (int c = 0; c < E; ++c) ssum += __expf(Sl[tid][c] - m);
            float inv = 1.0f / ssum;
            gate[t0 + tid] = inv;
            idx[t0 + tid] = am;
            sm[tid] = m;
            sinv[tid] = inv;
            sidx[tid] = am;
        }
        __syncthreads();
        if (tid < E) {    // column phase: me partials + TRANSPOSED histogram
            float cs = 0.f;
            int cnt = 0;
#pragma unroll 8
            for (int r = 0; r < 32; ++r) {
                cs += __expf(Sl[r][tid] - sm[r]) * sinv[r];
                cnt += (sidx[r] == tid) ? 1 : 0;
            }
            me_part[bid * E + tid] = cs;
            cnt_gT[tid * GEMM_BLOCKS + bid] = cnt;   // [e][block]
        }
    } else {
        // block-chunked zero-fill of dispatch half (+ counts zeros, harmless)
        int fb = bid - GEMM_BLOCKS;
        if (fb == 0 && tid == 0) {
            out[1 + SEC] = 0.f; out[2 + SEC] = 0.f; out[3 + SEC] = 0.f;
        }
        unsigned base = B0 + (unsigned)fb * CH;
        f32x4 z = {0.f, 0.f, 0.f, 0.f};
        f32x4* o4 = (f32x4*)out;
        for (unsigned j = tid; j < CH; j += 512u) {
            unsigned i = base + j;
            if (i < N4END) o4[i] = z;
        }
    }
}

// ---------------- K2: merge-fill with INLINE rank (coalesced prefix) ---------
// Blocks [0,2048): 4 tokens each. Phase A: wave k computes token k's slot from
//   cnt_gT (prefix over GEMM blocks < t/32 — lane-consecutive reads now) + a
//   32-lane ballot rank within the token's GEMM block. Phase B: R21's proven
//   pure-write merge of the combine span + dispatch one.
// Block 2048: counts[0..63] + l_aux from cnt_gT/me_part (deterministic).
__global__ __launch_bounds__(256) void k_merge(const int* __restrict__ idx,
                                               const float* __restrict__ gate,
                                               const float* __restrict__ me_part,
                                               const int* __restrict__ cnt_gT,
                                               float* __restrict__ out) {
    int bid = blockIdx.x;
    int tid = threadIdx.x;
    if (bid == 2048) {   // counts + l_aux
        __shared__ int ic[4][64];
        __shared__ float fc[4][64];
        int e = tid & 63, q = tid >> 6;
        int cnt = 0; float me = 0.f;
        for (int b = q * 64; b < q * 64 + 64; ++b) {
            cnt += cnt_gT[e * GEMM_BLOCKS + b];
            me += me_part[b * E + e];
        }
        ic[q][e] = cnt; fc[q][e] = me;
        __syncthreads();
        if (tid < E) {
            int c2 = ic[0][tid] + ic[1][tid] + ic[2][tid] + ic[3][tid];
            float m2 = fc[0][tid] + fc[1][tid] + fc[2][tid] + fc[3][tid];
            out[1 + 2 * (size_t)SEC + tid] = (float)c2;   // exp_counts (pre-drop)
            float la = m2 * (1.0f / (float)S) * ((float)c2 / (float)S) * (float)E;
#pragma unroll
            for (int off = 32; off > 0; off >>= 1)
                la += __shfl_down(la, off, 64);
            if (tid == 0) out[0] = la;                    // l_aux
        }
        return;
    }
    __shared__ int stg[4];
    __shared__ float sgv[4];
    {   // Phase A: wave k owns token t = bid*4 + k
        int k = tid >> 6;
        int lane = tid & 63;
        int t = bid * 4 + k;
        int e = idx[t];
        int B = t >> 5;                    // GEMM block of token t
        int r = t & 31;                    // position within GEMM block
        const int* ce = cnt_gT + e * GEMM_BLOCKS;
        int pre = 0;
#pragma unroll
        for (int c = 0; c < 4; ++c) {      // prefix over GEMM blocks < B
            int b = lane + c * 64;         // lane-consecutive -> coalesced
            if (b < B) pre += ce[b];
        }
#pragma unroll
        for (int off = 32; off > 0; off >>= 1)
            pre += __shfl_down(pre, off, 64);
        // intra-block rank: tokens [32B, t) routed to e
        bool m = (lane < r) && (idx[(B << 5) + lane] == e);
        int rank = __popcll(__ballot(m));
        if (lane == 0) {
            int p = pre + rank;            // pre-drop position within expert
            stg[k] = (p < CAP) ? e * CAP + p : -1;
            sgv[k] = gate[t];
        }
    }
    __syncthreads();
    // Phase B: pure-write merge (R21 proven)
    f32x4* o4 = (f32x4*)out;
#pragma unroll
    for (int k = 0; k < 4; ++k) {
        int t = bid * 4 + k;
        int tgt = stg[k];                  // local slot in [0,8192) or -1
        float gv = sgv[k];
        for (int j = 1 + tid; j < 2048; j += 256) {
            int base = 4 * j - 1;
            f32x4 v;
            v[0] = (tgt == base) ? gv : 0.f;
            v[1] = (tgt == base + 1) ? gv : 0.f;
            v[2] = (tgt == base + 2) ? gv : 0.f;
            v[3] = (tgt == base + 3) ? gv : 0.f;
            o4[2048u * (unsigned)t + (unsigned)j] = v;
        }
        if (tid < 4) {   // boundary scalars: local c = 0,1,2,8191
            int c = (tid < 3) ? tid : 8191;
            out[1 + (size_t)t * 8192 + c] = (tgt == c) ? gv : 0.f;
        }
        if (tid == 4 && tgt >= 0)          // dispatch one (half zeroed by K1)
            out[1 + SEC + (size_t)t * 8192 + tgt] = 1.0f;
    }
}

extern "C" void kernel_launch(void* const* d_in, const int* in_sizes, int n_in,
                              void* d_out, int out_size, void* d_ws, size_t ws_size,
                              hipStream_t stream) {
    const float* x = (const float*)d_in[0];      // [S, Dm] fp32
    const float* w = (const float*)d_in[1];      // [E, Dm] fp32
    float* out = (float*)d_out;

    // ws layout
    float* me_part = (float*)d_ws;               // [256][64] = 64 KB
    float* gate = me_part + GEMM_BLOCKS * E;     // S floats
    int* idx = (int*)(gate + S);                 // S ints
    int* cnt_gT = idx + S;                       // [64][256] = 64 KB (transposed)

    k_main<<<dim3(GEMM_BLOCKS + FILL_BLOCKS), dim3(512), 0, stream>>>(
        x, w, gate, idx, me_part, cnt_gT, out);
    k_merge<<<dim3(2049), dim3(256), 0, stream>>>(
        idx, gate, me_part, cnt_gT, out);
}

// Round 26
// 128.874 us; speedup vs baseline: 1.1389x; 1.1389x over previous
//
#include <hip/hip_runtime.h>
#include <cstdint>
#include <cstddef>

#define S 8192
#define Dm 1024
#define E 64
#define CAP 128
#define SEC 67108864ull   // S*E*CAP
// out layout (float32 elements), out_size = 1 + 2*SEC + 64 = 134,217,793:
//   [0] l_aux | [1,1+SEC) combine | [1+SEC,1+2SEC) dispatch | [1+2SEC,+64) counts
// Coverage map (every element written every call):
//   K1 fill: elements [1+SEC+3, 134217792) zeroed via chunks [16777217,33554448)
//            + scalar zeros at out[1+SEC],out[2+SEC],out[3+SEC]; la_ws zeroed
//   K2: counts[0..63] written unconditionally (incl. element 134217792)
//   K3: combine elements [1, 1+SEC) = final values; dispatch 1.0s; out[0]=l_aux

#define GEMM_BLOCKS 256   // 32 tokens x 64 experts (R17-verified MFMA GEMM)
#define FILL_BLOCKS 1792
#define B0 16777217u      // first aligned chunk of the dispatch-half fill
#define TCH 16777231u     // total chunks to fill
#define CH 9363u          // ceil(TCH / FILL_BLOCKS)
#define N4END 33554448u
#define WSCALE 4096.0f
#define INV_WSCALE (1.0f / 4096.0f)

typedef float f32x4 __attribute__((ext_vector_type(4)));
typedef _Float16 f16x4 __attribute__((ext_vector_type(4)));
typedef _Float16 f16x8 __attribute__((ext_vector_type(8)));

#define CV4(H, L, ROW, COL, V, SCALE) do {                                     \
    f16x4 hh, ll; float t_;                                                    \
    t_ = (V).x * (SCALE); hh[0] = (_Float16)t_; ll[0] = (_Float16)(t_ - (float)hh[0]); \
    t_ = (V).y * (SCALE); hh[1] = (_Float16)t_; ll[1] = (_Float16)(t_ - (float)hh[1]); \
    t_ = (V).z * (SCALE); hh[2] = (_Float16)t_; ll[2] = (_Float16)(t_ - (float)hh[2]); \
    t_ = (V).w * (SCALE); hh[3] = (_Float16)t_; ll[3] = (_Float16)(t_ - (float)hh[3]); \
    *(f16x4*)&H[ROW][COL] = hh;                                                \
    *(f16x4*)&L[ROW][COL] = ll;                                                \
} while (0)

// ---------------- K1: MFMA GEMM+softmax (R17-verified) + dispatch-half fill --
__global__ __launch_bounds__(512) void k_main(const float* __restrict__ x,
                                              const float* __restrict__ w,
                                              float* __restrict__ gate,
                                              int* __restrict__ idx,
                                              float* __restrict__ me_part,
                                              int* __restrict__ cnt_g,
                                              float* __restrict__ la_ws,
                                              float* __restrict__ out) {
    int bid = blockIdx.x;
    int tid = threadIdx.x;
    if (bid < GEMM_BLOCKS) {
        __shared__ _Float16 Ah[32][72];
        __shared__ _Float16 Alo[32][72];
        __shared__ _Float16 Wh[64][72];
        __shared__ _Float16 Wlo[64][72];
        __shared__ float Sl[32][66];
        __shared__ float sm[32];
        __shared__ float sinv[32];
        __shared__ int sidx[32];
        int t0 = bid * 32;
        int ar = tid >> 4;                 // 0..31
        int ac = (tid & 15) * 4;
        int wr = tid >> 3;                 // 0..63
        int wc = (tid & 7) * 8;
        const float* asrc = x + (size_t)(t0 + ar) * Dm + ac;
        const float* wsrc = w + (size_t)wr * Dm + wc;

        int wv = tid >> 6;
        int l = tid & 63;
        int lr = l & 15;
        int lg = l >> 4;
        int mt = wv & 1;
        int nt = wv >> 1;
        f32x4 acc = {0.f, 0.f, 0.f, 0.f};

        float4 pa = *(const float4*)(asrc + 0);
        float4 pw0 = *(const float4*)(wsrc + 0);
        float4 pw1 = *(const float4*)(wsrc + 4);
        float4 qa = *(const float4*)(asrc + 64);
        float4 qw0 = *(const float4*)(wsrc + 64);
        float4 qw1 = *(const float4*)(wsrc + 68);

#define WRITE_LDS(A, W0, W1)                                                   \
        CV4(Ah, Alo, ar, ac, A, 1.0f);                                         \
        CV4(Wh, Wlo, wr, wc, W0, WSCALE);                                      \
        CV4(Wh, Wlo, wr, (wc + 4), W1, WSCALE);
#define LOADP(KB)                                                              \
        pa = *(const float4*)(asrc + (KB));                                    \
        pw0 = *(const float4*)(wsrc + (KB));                                   \
        pw1 = *(const float4*)(wsrc + (KB) + 4);
#define LOADQ(KB)                                                              \
        qa = *(const float4*)(asrc + (KB));                                    \
        qw0 = *(const float4*)(wsrc + (KB));                                   \
        qw1 = *(const float4*)(wsrc + (KB) + 4);
#define INNER_MFMA                                                             \
        _Pragma("unroll")                                                      \
        for (int ks = 0; ks < 2; ++ks) {                                       \
            int kc = ks * 32 + lg * 8;                                         \
            f16x8 ah = *(const f16x8*)&Ah[mt * 16 + lr][kc];                   \
            f16x8 al = *(const f16x8*)&Alo[mt * 16 + lr][kc];                  \
            f16x8 bh = *(const f16x8*)&Wh[nt * 16 + lr][kc];                   \
            f16x8 bl = *(const f16x8*)&Wlo[nt * 16 + lr][kc];                  \
            acc = __builtin_amdgcn_mfma_f32_16x16x32_f16(ah, bh, acc, 0, 0, 0); \
            acc = __builtin_amdgcn_mfma_f32_16x16x32_f16(al, bh, acc, 0, 0, 0); \
            acc = __builtin_amdgcn_mfma_f32_16x16x32_f16(ah, bl, acc, 0, 0, 0); \
        }

        for (int ch = 0; ch < 16; ch += 2) {
            __syncthreads();
            WRITE_LDS(pa, pw0, pw1)
            __syncthreads();
            if (ch + 2 < 16) { LOADP((ch + 2) * 64) }
            INNER_MFMA
            __syncthreads();
            WRITE_LDS(qa, qw0, qw1)
            __syncthreads();
            if (ch + 3 < 16) { LOADQ((ch + 3) * 64) }
            INNER_MFMA
        }
#undef WRITE_LDS
#undef LOADP
#undef LOADQ
#undef INNER_MFMA
        __syncthreads();
        // D -> Sl (R16/R17-verified C/D layout: row = lg*4 + r, col = lr)
#pragma unroll
        for (int r = 0; r < 4; ++r)
            Sl[mt * 16 + lg * 4 + r][nt * 16 + lr] = acc[r] * INV_WSCALE;
        __syncthreads();
        if (tid < 32) {   // row phase: first-index argmax + exp-sum
            float m = Sl[tid][0];
            int am = 0;
#pragma unroll
            for (int c = 1; c < E; ++c) {
                float v = Sl[tid][c];
                if (v > m) { m = v; am = c; }
            }
            float ssum = 0.f;
#pragma unroll
            for (int c = 0; c < E; ++c) ssum += __expf(Sl[tid][c] - m);
            float inv = 1.0f / ssum;
            gate[t0 + tid] = inv;
            idx[t0 + tid] = am;
            sm[tid] = m;
            sinv[tid] = inv;
            sidx[tid] = am;
        }
        __syncthreads();
        if (tid < E) {    // column phase: me partials + exact expert histogram
            float cs = 0.f;
            int cnt = 0;
#pragma unroll 8
            for (int r = 0; r < 32; ++r) {
                cs += __expf(Sl[r][tid] - sm[r]) * sinv[r];
                cnt += (sidx[r] == tid) ? 1 : 0;
            }
            me_part[bid * E + tid] = cs;
            cnt_g[bid * E + tid] = cnt;
        }
    } else {
        // block-chunked zero-fill of dispatch half + counts[0..62]
        int fb = bid - GEMM_BLOCKS;
        if (fb == 0 && tid == 0) {
            out[1 + SEC] = 0.f; out[2 + SEC] = 0.f; out[3 + SEC] = 0.f;
            la_ws[0] = 0.f;
        }
        unsigned base = B0 + (unsigned)fb * CH;
        f32x4 z = {0.f, 0.f, 0.f, 0.f};
        f32x4* o4 = (f32x4*)out;
        for (unsigned j = tid; j < CH; j += 512u) {
            unsigned i = base + j;
            if (i < N4END) o4[i] = z;
        }
    }
}

// ---------------- K2: quartered scan -> tg[], counts, l_aux accum ------------
// R20's proven quartered ballot scan; writes tg[t] = {local slot or -1, gate}
// for EVERY token instead of scattering into out (combine isn't zeroed yet).
__global__ __launch_bounds__(256) void k_scan(const int* __restrict__ idx,
                                              const float* __restrict__ gate,
                                              const float* __restrict__ me_part,
                                              const int* __restrict__ cnt_g,
                                              float2* __restrict__ tg,
                                              float* __restrict__ la_ws,
                                              float* __restrict__ out) {
    int e = blockIdx.x >> 2;
    int q = blockIdx.x & 3;
    int tid = threadIdx.x;
    int lane = tid & 63;
    int wid = tid >> 6;
    __shared__ int wsum[4];
    __shared__ int ired[256];
    __shared__ float red[256];
    int nb = q << 6;
    int a = 0;
    for (int b = tid; b < nb; b += 256) a += cnt_g[b * E + e];
    ired[tid] = a;
    __syncthreads();
    for (int s2 = 128; s2 > 0; s2 >>= 1) {
        if (tid < s2) ired[tid] += ired[tid + s2];
        __syncthreads();
    }
    int running = ired[0];
    __syncthreads();
    for (int ch = 0; ch < 8; ++ch) {
        int t = q * 2048 + ch * 256 + tid;
        bool f = (idx[t] == e);
        unsigned long long b = __ballot(f);
        int pre = __popcll(b & ((1ull << lane) - 1ull));
        if (lane == 0) wsum[wid] = __popcll(b);
        __syncthreads();
        int off = running;
#pragma unroll
        for (int w2 = 0; w2 < 4; ++w2)
            if (w2 < wid) off += wsum[w2];
        int p = off + pre;
        if (f) {   // every token written exactly once (by its argmax expert)
            int tgt = (p < CAP) ? e * CAP + p : -1;
            tg[t] = make_float2(__int_as_float(tgt), gate[t]);
        }
        running += wsum[0] + wsum[1] + wsum[2] + wsum[3];
        __syncthreads();
    }
    if (q == 3) {
        red[tid] = me_part[tid * E + e];
        __syncthreads();
        for (int s2 = 128; s2 > 0; s2 >>= 1) {
            if (tid < s2) red[tid] += red[tid + s2];
            __syncthreads();
        }
        if (tid == 0) {
            out[1 + 2 * (size_t)SEC + e] = (float)running;   // exp_counts
            float la = red[0] * (1.0f / (float)S) *
                       ((float)running / (float)S) * (float)E;
            atomicAdd(la_ws, la);
        }
    }
}

// ---------------- K3: merge-fill combine half + dispatch ones + l_aux --------
// Pure-write kernel: 2048 blocks x 256 thr, 4 tokens/block. Per token t the
// combine span out[1+8192t .. +8192) is written DIRECTLY with final values
// (zeros except slot tgt = gate): 2047 aligned float4 (4 cmp + 4 cndmask each;
// no dynamic vector index, rule #20) + 4 boundary scalars. Runs at fill BW —
// no concurrent reads to interfere (the R19/R20-diagnosed wall).
__global__ __launch_bounds__(256) void k_merge(const float2* __restrict__ tg,
                                               const float* __restrict__ la_ws,
                                               float* __restrict__ out) {
    int bid = blockIdx.x;
    int tid = threadIdx.x;
    if (bid == 0 && tid == 0) out[0] = la_ws[0];   // l_aux (K2 complete)
    f32x4* o4 = (f32x4*)out;
#pragma unroll
    for (int k = 0; k < 4; ++k) {
        int t = bid * 4 + k;
        float2 g = tg[t];
        int tgt = __float_as_int(g.x);     // local slot in [0,8192) or -1
        float gv = g.y;
        // aligned chunks j in [1,2048): global chunk 2048t+j covers local
        // combine indices [4j-1, 4j+3)
        for (int j = 1 + tid; j < 2048; j += 256) {
            int base = 4 * j - 1;
            f32x4 v;
            v[0] = (tgt == base) ? gv : 0.f;
            v[1] = (tgt == base + 1) ? gv : 0.f;
            v[2] = (tgt == base + 2) ? gv : 0.f;
            v[3] = (tgt == base + 3) ? gv : 0.f;
            o4[2048u * (unsigned)t + (unsigned)j] = v;
        }
        if (tid < 4) {   // boundary scalars: local c = 0,1,2,8191
            int c = (tid < 3) ? tid : 8191;
            out[1 + (size_t)t * 8192 + c] = (tgt == c) ? gv : 0.f;
        }
        if (tid == 4 && tgt >= 0)   // dispatch one (half zeroed by K1)
            out[1 + SEC + (size_t)t * 8192 + tgt] = 1.0f;
    }
}

extern "C" void kernel_launch(void* const* d_in, const int* in_sizes, int n_in,
                              void* d_out, int out_size, void* d_ws, size_t ws_size,
                              hipStream_t stream) {
    const float* x = (const float*)d_in[0];      // [S, Dm] fp32
    const float* w = (const float*)d_in[1];      // [E, Dm] fp32
    float* out = (float*)d_out;

    // ws layout
    float* me_part = (float*)d_ws;               // [256][64] = 64 KB
    float* gate = me_part + GEMM_BLOCKS * E;     // S floats
    int* idx = (int*)(gate + S);                 // S ints
    int* cnt_g = idx + S;                        // [256][64] = 64 KB
    float2* tg = (float2*)(cnt_g + GEMM_BLOCKS * E);   // S float2 = 64 KB
    float* la_ws = (float*)(tg + S);             // 1 float

    k_main<<<dim3(GEMM_BLOCKS + FILL_BLOCKS), dim3(512), 0, stream>>>(
        x, w, gate, idx, me_part, cnt_g, la_ws, out);
    k_scan<<<dim3(256), dim3(256), 0, stream>>>(
        idx, gate, me_part, cnt_g, tg, la_ws, out);
    k_merge<<<dim3(2048), dim3(256), 0, stream>>>(tg, la_ws, out);
}